// Round 3
// baseline (438.351 us; speedup 1.0000x reference)
//
#include <hip/hip_runtime.h>

// TGRec fused forward, MI355X (gfx950), all f32.
// R6 structure:
//   k_prep : blocks 0..511  -> W = (w_qs_h @ w_ks_h^T) * 1/sqrt(128) (256x512)
//            blocks 512..1023 -> M[u][c] = sum_j w_vs[t][j]*fc_w[j][c]
//                                (u = h*256+t, j in head h's 128 cols; 512x256)
//   k_qk   : QK = [src|src_t] @ W                    (validated R4/R5)
//   k_attn : 1 batch/block; pass-1 lane=row keeps kv in registers; S computed
//            by in-register shfl_xor(1..8) group reduction + LDS combine —
//            NO second pass over seq/seqt (removes ~134MB refetch).
//   k_epi  : 8 batches/block (grid 512, halves weight L2 traffic); single
//            K=512 x-stage via M (replaces ov+fc stages); wave-parallel LN.
// S = sum_n softmax_n * k_in[n]  (associativity: V-projection deferred).

__device__ __forceinline__ void fma4(float4& a, float s, const float4& w) {
  a.x = fmaf(s, w.x, a.x); a.y = fmaf(s, w.y, a.y);
  a.z = fmaf(s, w.z, a.z); a.w = fmaf(s, w.w, a.w);
}
__device__ __forceinline__ float dot4(const float4& a, const float4& b) {
  return a.x * b.x + a.y * b.y + a.z * b.z + a.w * b.w;
}

// ---------------------------------------------------------------------------
// K-1: fused weight prep. W path: W[c, h*256+j] = (1/sqrt(128)) *
//   sum_d w_qs[c, h*128+d]*w_ks[j, h*128+d].  M path: one block per u row.
__global__ __launch_bounds__(256) void k_prep(const float* __restrict__ w_qs,
                                              const float* __restrict__ w_ks,
                                              const float* __restrict__ w_vs,
                                              const float* __restrict__ fc_w,
                                              float* __restrict__ W,
                                              float* __restrict__ M) {
  const int bid = blockIdx.x;
  const int tid = threadIdx.x;
  if (bid < 512) {
    const int idx = bid * 256 + tid;  // 0..131071
    const int c = idx >> 9;           // 0..255
    const int col = idx & 511;        // 0..511
    const int h = col >> 8;
    const int j = col & 255;
    const float* a = w_qs + c * 256 + h * 128;
    const float* bk = w_ks + j * 256 + h * 128;
    float acc = 0.f;
#pragma unroll
    for (int d = 0; d < 128; d += 4)
      acc += dot4(*(const float4*)&a[d], *(const float4*)&bk[d]);
    W[idx] = acc * 0.08838834764831845f;  // fold 1/sqrt(128)
  } else {
    const int u = bid - 512;          // 0..511
    const int h = u >> 8, t = u & 255;
    const float* wv = w_vs + t * 256 + h * 128;   // uniform across threads
    const float* fw = fc_w + (h * 128) * 256;
    float acc = 0.f;
    for (int jj = 0; jj < 128; jj += 4) {
      acc = fmaf(wv[jj + 0], fw[(jj + 0) * 256 + tid], acc);
      acc = fmaf(wv[jj + 1], fw[(jj + 1) * 256 + tid], acc);
      acc = fmaf(wv[jj + 2], fw[(jj + 2) * 256 + tid], acc);
      acc = fmaf(wv[jj + 3], fw[(jj + 3) * 256 + tid], acc);
    }
    M[u * 256 + tid] = acc;
  }
}

// ---------------------------------------------------------------------------
// K0: QK = qin @ W   (4096x256 @ 256x512). [validated R4/R5]
__global__ __launch_bounds__(256) void k_qk(const float* __restrict__ src,
                                            const float* __restrict__ srct,
                                            const float* __restrict__ W,
                                            float* __restrict__ QK) {
  __shared__ float sQ[16 * 256];
  const int tid = threadIdx.x;
  const int rb = (blockIdx.x >> 1) * 16;
  const int ch = (blockIdx.x & 1) * 256;
  {
    const int r = tid >> 4;
    const int cb = (tid & 15) * 16;
#pragma unroll
    for (int i = 0; i < 4; ++i) {
      const int c = cb + i * 4;
      float4 v = (c < 128) ? *(const float4*)&src[(rb + r) * 128 + c]
                           : *(const float4*)&srct[(rb + r) * 128 + (c - 128)];
      *(float4*)&sQ[r * 256 + c] = v;
    }
  }
  __syncthreads();
  const int rg = tid >> 6;
  const int cg = tid & 63;
  const int col = ch + cg * 4;
  float4 acc[4] = {};
  for (int k = 0; k < 256; k += 4) {
    const float4 w0 = *(const float4*)&W[(k + 0) * 512 + col];
    const float4 w1 = *(const float4*)&W[(k + 1) * 512 + col];
    const float4 w2 = *(const float4*)&W[(k + 2) * 512 + col];
    const float4 w3 = *(const float4*)&W[(k + 3) * 512 + col];
#pragma unroll
    for (int r = 0; r < 4; ++r) {
      const float4 a = *(const float4*)&sQ[(rg * 4 + r) * 256 + k];
      fma4(acc[r], a.x, w0); fma4(acc[r], a.y, w1);
      fma4(acc[r], a.z, w2); fma4(acc[r], a.w, w3);
    }
  }
#pragma unroll
  for (int r = 0; r < 4; ++r)
    *(float4*)&QK[(rb + rg * 4 + r) * 512 + col] = acc[r];
}

// ---------------------------------------------------------------------------
// K1: attention, 1 batch/block (grid 4096), single pass over seq/seqt.
// Wave w owns concat dims [64w,64w+64); lane = row. kv stays in registers;
// S = sum_n a_n * kv_n computed by shfl_xor(1,2,4,8) within 16-lane groups,
// 4 group-partials/wave written to LDS, combined by all 256 threads.
__global__ __launch_bounds__(256) void k_attn(const float* __restrict__ seq,
                                              const float* __restrict__ seqt,
                                              const unsigned int* __restrict__ mw,
                                              float* QKS,
                                              float* __restrict__ att) {
  __shared__ float sqk[512];
  __shared__ float part0[4][64];
  __shared__ float part1[4][64];
  __shared__ float sp[2][4][4][68];  // [head][wave][group16][dim] (+pad)
  const int tid = threadIdx.x;
  const int lane = tid & 63;
  const int w = tid >> 6;
  const int b = blockIdx.x;

  if (tid < 128)
    *(float4*)&sqk[tid * 4] = *(const float4*)&QKS[b * 512 + tid * 4];
  const bool masked = (mw[b * 64 + lane] != 0u);
  __syncthreads();

  // Pass 1: wave w owns concat dims [64w, 64w+64); kv kept live in regs.
  const float* rowp = (w < 2) ? (seq + b * 8192 + lane * 128 + w * 64)
                              : (seqt + b * 8192 + lane * 128 + (w - 2) * 64);
  float4 kv[16];
#pragma unroll
  for (int i = 0; i < 16; ++i) kv[i] = make_float4(0.f, 0.f, 0.f, 0.f);
  float p0 = 0.f, p1 = 0.f;
  if (!masked) {
    const float* q0 = &sqk[w * 64];
    const float* q1 = &sqk[256 + w * 64];
#pragma unroll
    for (int i = 0; i < 16; ++i) {
      kv[i] = *(const float4*)&rowp[i * 4];
      p0 += dot4(kv[i], *(const float4*)&q0[i * 4]);
      p1 += dot4(kv[i], *(const float4*)&q1[i * 4]);
    }
  }
  part0[w][lane] = p0;
  part1[w][lane] = p1;
  __syncthreads();

  const float fp0 =
      part0[0][lane] + part0[1][lane] + part0[2][lane] + part0[3][lane];
  const float fp1 =
      part1[0][lane] + part1[1][lane] + part1[2][lane] + part1[3][lane];
  const float e0 = masked ? 0.f : __expf(fp0);
  const float e1 = masked ? 0.f : __expf(fp1);
  float l0 = e0, l1 = e1;
#pragma unroll
  for (int off = 32; off >= 1; off >>= 1) {
    l0 += __shfl_xor(l0, off);
    l1 += __shfl_xor(l1, off);
  }
  const float a0 = e0 / l0;  // masked: e=0 -> a=0, kv=0 (double-safe)
  const float a1 = e1 / l1;
  if (w == 0) {
    att[b * 64 + lane] = a0;
    att[4096 * 64 + b * 64 + lane] = a1;
  }

  // In-register S reduction: 4 stages within 16-lane groups, then LDS.
  const int g = lane >> 4;
#pragma unroll
  for (int i = 0; i < 16; ++i) {
    float4 t0, t1;
    t0.x = kv[i].x * a0; t0.y = kv[i].y * a0;
    t0.z = kv[i].z * a0; t0.w = kv[i].w * a0;
    t1.x = kv[i].x * a1; t1.y = kv[i].y * a1;
    t1.z = kv[i].z * a1; t1.w = kv[i].w * a1;
#pragma unroll
    for (int off = 1; off <= 8; off <<= 1) {
      t0.x += __shfl_xor(t0.x, off); t0.y += __shfl_xor(t0.y, off);
      t0.z += __shfl_xor(t0.z, off); t0.w += __shfl_xor(t0.w, off);
      t1.x += __shfl_xor(t1.x, off); t1.y += __shfl_xor(t1.y, off);
      t1.z += __shfl_xor(t1.z, off); t1.w += __shfl_xor(t1.w, off);
    }
    if ((lane & 15) == 0) {
      *(float4*)&sp[0][w][g][i * 4] = t0;
      *(float4*)&sp[1][w][g][i * 4] = t1;
    }
  }
  __syncthreads();

  // Combine group partials; thread tid -> dim (tid>>6)*64 + (tid&63).
  {
    const int wo = tid >> 6, j = tid & 63;
    const float s0 =
        sp[0][wo][0][j] + sp[0][wo][1][j] + sp[0][wo][2][j] + sp[0][wo][3][j];
    const float s1 =
        sp[1][wo][0][j] + sp[1][wo][1][j] + sp[1][wo][2][j] + sp[1][wo][3][j];
    QKS[b * 512 + wo * 64 + j] = s0;
    QKS[b * 512 + 256 + wo * 64 + j] = s1;
  }
}

// ---------------------------------------------------------------------------
// K2: epilogue — 8 batches/block (grid 512). x = S @ M + fc_b + qin (K=512),
// wave-parallel LN, fc1+relu, fc2. Weight L2 traffic halved vs 4-batch.
__global__ __launch_bounds__(256) void k_epi(
    const float* __restrict__ S, const float* __restrict__ src,
    const float* __restrict__ srct, const float* __restrict__ M,
    const float* __restrict__ fc_b, const float* __restrict__ ln_g,
    const float* __restrict__ ln_b, const float* __restrict__ fc1_w,
    const float* __restrict__ fc1_b, const float* __restrict__ fc2_w,
    const float* __restrict__ fc2_b, float* __restrict__ out) {
  __shared__ float sv[8][512];
  __shared__ float qin[8][256];
  __shared__ float hcat[8][384];
  __shared__ float h1[8][128];
  __shared__ float red[4][8][2];  // [wave][g][sum, sumsq]
  const int tid = threadIdx.x;
  const int lane = tid & 63;
  const int wv = tid >> 6;
  const int b0 = blockIdx.x * 8;

  // load S rows: 8 x 512 floats
#pragma unroll
  for (int i = 0; i < 4; ++i) {
    const int f4 = i * 256 + tid;      // 0..1023
    const int g = f4 >> 7;
    const int c = (f4 & 127) * 4;
    *(float4*)&sv[g][c] = *(const float4*)&S[(b0 + g) * 512 + c];
  }
  // load q_in = [src | src_t]: 8 x 256 floats
#pragma unroll
  for (int i = 0; i < 2; ++i) {
    const int f4 = i * 256 + tid;      // 0..511
    const int g = f4 >> 6;
    const int c = (f4 & 63) * 4;
    float4 v = (c < 128) ? *(const float4*)&src[(b0 + g) * 128 + c]
                         : *(const float4*)&srct[(b0 + g) * 128 + (c - 128)];
    *(float4*)&qin[g][c] = v;
  }
  __syncthreads();

  // x[g] = sv[g] @ M[:,tid] + fc_b[tid] + qin[g][tid]   (K=512, registers)
  float x[8];
  {
    float acc[8] = {};
    for (int d = 0; d < 512; d += 4) {
      const float w0 = M[(d + 0) * 256 + tid];
      const float w1 = M[(d + 1) * 256 + tid];
      const float w2 = M[(d + 2) * 256 + tid];
      const float w3 = M[(d + 3) * 256 + tid];
#pragma unroll
      for (int g = 0; g < 8; ++g) {
        const float4 s4 = *(const float4*)&sv[g][d];
        acc[g] = fmaf(s4.x, w0, acc[g]);
        acc[g] = fmaf(s4.y, w1, acc[g]);
        acc[g] = fmaf(s4.z, w2, acc[g]);
        acc[g] = fmaf(s4.w, w3, acc[g]);
      }
    }
    const float fb = fc_b[tid];
#pragma unroll
    for (int g = 0; g < 8; ++g) x[g] = acc[g] + fb + qin[g][tid];
  }

  // wave-parallel LayerNorm stats
#pragma unroll
  for (int g = 0; g < 8; ++g) {
    float s = x[g];
    float q = x[g] * x[g];
#pragma unroll
    for (int off = 32; off >= 1; off >>= 1) {
      s += __shfl_xor(s, off);
      q += __shfl_xor(q, off);
    }
    if (lane == 0) {
      red[wv][g][0] = s;
      red[wv][g][1] = q;
    }
  }
  __syncthreads();
  {
    const float gg = ln_g[tid], bb = ln_b[tid];
#pragma unroll
    for (int g = 0; g < 8; ++g) {
      const float s = red[0][g][0] + red[1][g][0] + red[2][g][0] + red[3][g][0];
      const float q = red[0][g][1] + red[1][g][1] + red[2][g][1] + red[3][g][1];
      const float mu = s * (1.0f / 256.0f);
      const float rstd = rsqrtf(q * (1.0f / 256.0f) - mu * mu + 1e-5f);
      hcat[g][tid] = (x[g] - mu) * rstd * gg + bb;
    }
  }
  // hcat tail = src row (already staged in qin[g][0..127])
#pragma unroll
  for (int i = 0; i < 4; ++i) {
    const int idx = i * 256 + tid;     // 0..1023
    const int g = idx >> 7, c = idx & 127;
    hcat[g][256 + c] = qin[g][c];
  }
  __syncthreads();

  // fc1 + relu: col = tid&127, four g per thread
  {
    const int col = tid & 127;
    const int gp = (tid >> 7) * 4;
    float acc0 = fc1_b[col], acc1 = acc0, acc2 = acc0, acc3 = acc0;
    for (int d = 0; d < 384; d += 4) {
      const float w0 = fc1_w[(d + 0) * 128 + col];
      const float w1 = fc1_w[(d + 1) * 128 + col];
      const float w2 = fc1_w[(d + 2) * 128 + col];
      const float w3 = fc1_w[(d + 3) * 128 + col];
      const float4 a4 = *(const float4*)&hcat[gp][d];
      const float4 b4 = *(const float4*)&hcat[gp + 1][d];
      const float4 c4 = *(const float4*)&hcat[gp + 2][d];
      const float4 d4 = *(const float4*)&hcat[gp + 3][d];
      acc0 = fmaf(a4.x, w0, acc0); acc0 = fmaf(a4.y, w1, acc0);
      acc0 = fmaf(a4.z, w2, acc0); acc0 = fmaf(a4.w, w3, acc0);
      acc1 = fmaf(b4.x, w0, acc1); acc1 = fmaf(b4.y, w1, acc1);
      acc1 = fmaf(b4.z, w2, acc1); acc1 = fmaf(b4.w, w3, acc1);
      acc2 = fmaf(c4.x, w0, acc2); acc2 = fmaf(c4.y, w1, acc2);
      acc2 = fmaf(c4.z, w2, acc2); acc2 = fmaf(c4.w, w3, acc2);
      acc3 = fmaf(d4.x, w0, acc3); acc3 = fmaf(d4.y, w1, acc3);
      acc3 = fmaf(d4.z, w2, acc3); acc3 = fmaf(d4.w, w3, acc3);
    }
    h1[gp][col] = fmaxf(acc0, 0.f);
    h1[gp + 1][col] = fmaxf(acc1, 0.f);
    h1[gp + 2][col] = fmaxf(acc2, 0.f);
    h1[gp + 3][col] = fmaxf(acc3, 0.f);
  }
  __syncthreads();

  // fc2 -> merged
  {
    const int col = tid & 127;
    const int gp = (tid >> 7) * 4;
    float acc0 = fc2_b[col], acc1 = acc0, acc2 = acc0, acc3 = acc0;
    for (int d = 0; d < 128; d += 4) {
      const float w0 = fc2_w[(d + 0) * 128 + col];
      const float w1 = fc2_w[(d + 1) * 128 + col];
      const float w2 = fc2_w[(d + 2) * 128 + col];
      const float w3 = fc2_w[(d + 3) * 128 + col];
      const float4 a4 = *(const float4*)&h1[gp][d];
      const float4 b4 = *(const float4*)&h1[gp + 1][d];
      const float4 c4 = *(const float4*)&h1[gp + 2][d];
      const float4 d4 = *(const float4*)&h1[gp + 3][d];
      acc0 = fmaf(a4.x, w0, acc0); acc0 = fmaf(a4.y, w1, acc0);
      acc0 = fmaf(a4.z, w2, acc0); acc0 = fmaf(a4.w, w3, acc0);
      acc1 = fmaf(b4.x, w0, acc1); acc1 = fmaf(b4.y, w1, acc1);
      acc1 = fmaf(b4.z, w2, acc1); acc1 = fmaf(b4.w, w3, acc1);
      acc2 = fmaf(c4.x, w0, acc2); acc2 = fmaf(c4.y, w1, acc2);
      acc2 = fmaf(c4.z, w2, acc2); acc2 = fmaf(c4.w, w3, acc2);
      acc3 = fmaf(d4.x, w0, acc3); acc3 = fmaf(d4.y, w1, acc3);
      acc3 = fmaf(d4.z, w2, acc3); acc3 = fmaf(d4.w, w3, acc3);
    }
    out[(b0 + gp) * 128 + col] = acc0;
    out[(b0 + gp + 1) * 128 + col] = acc1;
    out[(b0 + gp + 2) * 128 + col] = acc2;
    out[(b0 + gp + 3) * 128 + col] = acc3;
  }
}

// ---------------------------------------------------------------------------
extern "C" void kernel_launch(void* const* d_in, const int* in_sizes, int n_in,
                              void* d_out, int out_size, void* d_ws,
                              size_t ws_size, hipStream_t stream) {
  (void)in_sizes; (void)n_in; (void)out_size; (void)ws_size;
  const float* src = (const float*)d_in[0];
  const float* srct = (const float*)d_in[1];
  const float* seq = (const float*)d_in[2];
  const float* seqt = (const float*)d_in[3];
  const unsigned int* mask = (const unsigned int*)d_in[4];
  const float* w_qs = (const float*)d_in[5];
  const float* w_ks = (const float*)d_in[6];
  const float* w_vs = (const float*)d_in[7];
  const float* fc_w = (const float*)d_in[8];
  const float* fc_b = (const float*)d_in[9];
  const float* ln_g = (const float*)d_in[10];
  const float* ln_b = (const float*)d_in[11];
  const float* fc1_w = (const float*)d_in[12];
  const float* fc1_b = (const float*)d_in[13];
  const float* fc2_w = (const float*)d_in[14];
  const float* fc2_b = (const float*)d_in[15];
  float* out = (float*)d_out;              // merged: 4096x128
  float* att = out + 4096 * 128;           // attn_sq: 8192x64
  float* W = (float*)d_ws;                 // 256x512 fused qk weight
  float* M = W + 256 * 512;                // 512x256 fused v/fc weight
  float* QKS = M + 512 * 256;              // 4096x512 (qk, then S in-place)
  k_prep<<<1024, 256, 0, stream>>>(w_qs, w_ks, w_vs, fc_w, W, M);
  k_qk<<<512, 256, 0, stream>>>(src, srct, W, QKS);
  k_attn<<<4096, 256, 0, stream>>>(seq, seqt, mask, QKS, att);
  k_epi<<<512, 256, 0, stream>>>(QKS, src, srct, M, fc_b, ln_g, ln_b, fc1_w,
                                 fc1_b, fc2_w, fc2_b, out);
}